// Round 12
// baseline (89.515 us; speedup 1.0000x reference)
//
#include <hip/hip_runtime.h>
#include <math.h>

#define N_NODES 40000
#define N_EDGES 640000
#define D_FEAT 128
#define SLOTS 48            // max degree cap; Poisson(16) => P(deg>48) ~ 1e-11/node
#define GPN 4               // 8-lane groups per node (2 nodes per wave)
#define MAXIT (SLOTS / GPN) // 12

// ---------------- build: ELL adjacency (histogram + scatter), int4-vectorized ----------------
__global__ void build_kernel(const int4* __restrict__ rows4, const int4* __restrict__ cols4,
                             int* __restrict__ count, int* __restrict__ ell) {
    int i = blockIdx.x * blockDim.x + threadIdx.x;
    if (i < N_EDGES / 4) {
        int4 r4 = rows4[i];
        int4 c4 = cols4[i];
        int k;
        k = atomicAdd(&count[r4.x], 1); if (k < SLOTS) ell[r4.x * SLOTS + k] = c4.x;
        k = atomicAdd(&count[r4.y], 1); if (k < SLOTS) ell[r4.y * SLOTS + k] = c4.y;
        k = atomicAdd(&count[r4.z], 1); if (k < SLOTS) ell[r4.z * SLOTS + k] = c4.z;
        k = atomicAdd(&count[r4.w], 1); if (k < SLOTS) ell[r4.w * SLOTS + k] = c4.w;
    }
}

// ---------------- fused dot + norms + exp + weighted aggregate ----------------
// TWO nodes per wave: lanes 0-31 = node A, lanes 32-63 = node B. Per node:
// four 8-lane groups, 16 feats/lane, depth-2 pipelined gathers, ~4-5 loop
// trips (steady state). No __syncthreads: each wave's LDS region is private.
__global__ __launch_bounds__(256)
void fused_kernel(const float* __restrict__ x, const float* __restrict__ beta,
                  const int* __restrict__ count, const int* __restrict__ ell,
                  float* __restrict__ out) {
    __shared__ float red[4][2][GPN][132];            // 132-pad: de-conflict stores (16.5 KiB)
    const int wid  = threadIdx.x >> 6;
    const int lane = threadIdx.x & 63;
    const int h    = lane >> 5;                      // half: which node
    const int l32  = lane & 31;
    const int g    = (lane >> 3) & 3;                // group 0..3 within half
    const int hl   = lane & 7;                       // lane in group
    const int node = blockIdx.x * 8 + wid * 2 + h;   // grid exact: 5000*8 = 40000
    const int deg  = min(count[node], SLOTS);
    const int NIT  = (deg + GPN - 1) >> 2;
    int mx = max(NIT, __shfl_xor(NIT, 32));          // wave-uniform trip count
    const int* eb = ell + node * SLOTS;

    // prefetch all ELL indices (independent loads, all in flight)
    int cidx[MAXIT];
    #pragma unroll
    for (int j = 0; j < MAXIT; j++) {
        int p = j * GPN + g;
        cidx[j] = (p < deg) ? eb[p] : node;
    }

    const float* xrow = x + (size_t)node * D_FEAT;
    const float4* xn = (const float4*)xrow;
    float4 a0 = xn[hl], a1 = xn[8 + hl], a2 = xn[16 + hl], a3 = xn[24 + hl];
    // self norm: reduce sum(a^2) within the 8-lane group (group holds the full row)
    float na2 = a0.x*a0.x + a0.y*a0.y + a0.z*a0.z + a0.w*a0.w
              + a1.x*a1.x + a1.y*a1.y + a1.z*a1.z + a1.w*a1.w
              + a2.x*a2.x + a2.y*a2.y + a2.z*a2.z + a2.w*a2.w
              + a3.x*a3.x + a3.y*a3.y + a3.z*a3.z + a3.w*a3.w;
    #pragma unroll
    for (int m = 1; m < 8; m <<= 1) na2 += __shfl_xor(na2, m);
    const float b0    = beta[0];
    const float scale = b0 * __frsqrt_rn(na2);       // beta / ||x_node||
    const float selfw = __expf(b0);                  // self-loop: cos = 1 -> alpha = beta
    float4 acc0 = {0,0,0,0}, acc1 = {0,0,0,0}, acc2 = {0,0,0,0}, acc3 = {0,0,0,0};
    float den = 0.f;

    // prologue: issue gathers for iterations 0 and 1 (one 128B line per group per instr)
    float4 A0, A1, A2, A3, B0, B1, B2, B3;
    {
        const float4* xc = (const float4*)(x + (size_t)cidx[0] * D_FEAT);
        A0 = xc[hl]; A1 = xc[8 + hl]; A2 = xc[16 + hl]; A3 = xc[24 + hl];
    }
    {
        const float4* xc = (const float4*)(x + (size_t)cidx[1] * D_FEAT);
        B0 = xc[hl]; B1 = xc[8 + hl]; B2 = xc[16 + hl]; B3 = xc[24 + hl];
    }

    #pragma unroll
    for (int j = 0; j < MAXIT; j++) {
        if (j >= mx) break;                          // wave-uniform exit
        float dot = a0.x*A0.x + a0.y*A0.y + a0.z*A0.z + a0.w*A0.w
                  + a1.x*A1.x + a1.y*A1.y + a1.z*A1.z + a1.w*A1.w
                  + a2.x*A2.x + a2.y*A2.y + a2.z*A2.z + a2.w*A2.w
                  + a3.x*A3.x + a3.y*A3.y + a3.z*A3.z + a3.w*A3.w;
        float nb2 = A0.x*A0.x + A0.y*A0.y + A0.z*A0.z + A0.w*A0.w
                  + A1.x*A1.x + A1.y*A1.y + A1.z*A1.z + A1.w*A1.w
                  + A2.x*A2.x + A2.y*A2.y + A2.z*A2.z + A2.w*A2.w
                  + A3.x*A3.x + A3.y*A3.y + A3.z*A3.z + A3.w*A3.w;
        #pragma unroll
        for (int m = 1; m < 8; m <<= 1) {            // 8-lane reduce of both values
            dot += __shfl_xor(dot, m);
            nb2 += __shfl_xor(nb2, m);
        }
        float w = (j * GPN + g < deg) ? __expf(dot * scale * __frsqrt_rn(nb2)) : 0.f;
        acc0.x += w*A0.x; acc0.y += w*A0.y; acc0.z += w*A0.z; acc0.w += w*A0.w;
        acc1.x += w*A1.x; acc1.y += w*A1.y; acc1.z += w*A1.z; acc1.w += w*A1.w;
        acc2.x += w*A2.x; acc2.y += w*A2.y; acc2.z += w*A2.z; acc2.w += w*A2.w;
        acc3.x += w*A3.x; acc3.y += w*A3.y; acc3.z += w*A3.z; acc3.w += w*A3.w;
        den += w;
        // rotate and issue gather for iteration j+2 (static index)
        A0 = B0; A1 = B1; A2 = B2; A3 = B3;
        int cn = (j + 2 < MAXIT) ? cidx[j + 2] : node;
        const float4* xc = (const float4*)(x + (size_t)cn * D_FEAT);
        B0 = xc[hl]; B1 = xc[8 + hl]; B2 = xc[16 + hl]; B3 = xc[24 + hl];
    }

    // den: reduce across the 4 groups of this half (8,16 stay within the half)
    den += __shfl_xor(den, 8);
    den += __shfl_xor(den, 16);

    // epilogue: per-group partials to LDS (wave-private region, no barrier needed)
    {
        float4* rb = (float4*)red[wid][h][g];        // 132-float region, 16B-aligned
        rb[      hl] = acc0;
        rb[ 8 + hl] = acc1;
        rb[16 + hl] = acc2;
        rb[24 + hl] = acc3;
    }
    // each lane reduces its float4 across the 4 groups of its half
    float4 s = {0.f, 0.f, 0.f, 0.f};
    #pragma unroll
    for (int q = 0; q < GPN; q++) {
        float4 t = ((const float4*)red[wid][h][q])[l32];
        s.x += t.x; s.y += t.y; s.z += t.z; s.w += t.w;
    }
    float4 xs = ((const float4*)xrow)[l32];          // self features (cache-hot re-read)
    float inv = 1.0f / (den + selfw);
    float4 o = { (s.x + selfw * xs.x) * inv, (s.y + selfw * xs.y) * inv,
                 (s.z + selfw * xs.z) * inv, (s.w + selfw * xs.w) * inv };
    ((float4*)(out + (size_t)node * D_FEAT))[l32] = o;
}

extern "C" void kernel_launch(void* const* d_in, const int* in_sizes, int n_in,
                              void* d_out, int out_size, void* d_ws, size_t ws_size,
                              hipStream_t stream) {
    const float* x    = (const float*)d_in[0];
    const float* beta = (const float*)d_in[1];
    const int*   row  = (const int*)d_in[2];        // edge_index[0] = destination
    const int*   col  = row + N_EDGES;              // edge_index[1] = source
    float*       out  = (float*)d_out;

    // workspace layout (4B elements, ~8 MB total)
    int* count = (int*)d_ws;                        // N
    int* ell   = count + N_NODES;                   // N * SLOTS

    hipMemsetAsync(count, 0, N_NODES * sizeof(int), stream);

    build_kernel<<<(N_EDGES / 4 + 255) / 256, 256, 0, stream>>>(
        (const int4*)row, (const int4*)col, count, ell);

    fused_kernel<<<N_NODES / 8, 256, 0, stream>>>(x, beta, count, ell, out);
}

// Round 13
// 87.199 us; speedup vs baseline: 1.0266x; 1.0266x over previous
//
#include <hip/hip_runtime.h>
#include <math.h>

#define N_NODES 40000
#define N_EDGES 640000
#define D_FEAT 128
#define SLOTS 48            // max degree cap; Poisson(16) => P(deg>48) ~ 1e-11/node
#define GPN 4               // 8-lane groups per node (2 nodes per wave)
#define MAXIT (SLOTS / GPN) // 12

// paired-float fma helpers (encourage v_pk_fma_f32 formation)
#define FMA2(ax, ay, bx, by, w, cx, cy) { cx = fmaf(ax, bx, cx); cy = fmaf(ay, by, cy); (void)w; }

// ---------------- node A: zero count + 1/||x_i|| (independent outputs, one dispatch) ----------------
__global__ void zero_rinv_kernel(const float* __restrict__ x, float* __restrict__ rinv,
                                 int* __restrict__ count) {
    int tid = blockIdx.x * blockDim.x + threadIdx.x;   // N_NODES*32 threads exact
    if (tid < N_NODES) count[tid] = 0;
    int node = tid >> 5;
    int l    = tid & 31;
    const float4* xp = (const float4*)(x + (size_t)node * D_FEAT);
    float4 v = xp[l];                                   // 32 lanes x 16B = 512B row
    float s = v.x*v.x + v.y*v.y + v.z*v.z + v.w*v.w;
    #pragma unroll
    for (int m = 1; m < 32; m <<= 1) s += __shfl_xor(s, m);   // stays within 32-lane group
    if (l == 0) rinv[node] = __frsqrt_rn(s);
}

// ---------------- node B: ELL adjacency build (histogram + scatter), scalar (R9 form) ----------------
__global__ void build_kernel(const int* __restrict__ row, const int* __restrict__ col,
                             int* __restrict__ count, int* __restrict__ ell) {
    int i = blockIdx.x * blockDim.x + threadIdx.x;
    if (i < N_EDGES) {
        int r = row[i];
        int rank = atomicAdd(&count[r], 1);
        if (rank < SLOTS) ell[r * SLOTS + rank] = col[i];
    }
}

// ---------------- node C: fused dot + exp + weighted aggregate ----------------
// Two nodes per wave (lanes 0-31 / 32-63), four 8-lane groups per node,
// coalesced 128B-line gathers, DEPTH-3 pipelined (A/B/C buffers), precomputed
// rinv (no in-loop norm). Wave-private LDS epilogue, no barrier.
__global__ __launch_bounds__(256)
void fused_kernel(const float* __restrict__ x, const float* __restrict__ beta,
                  const float* __restrict__ rinv, const int* __restrict__ count,
                  const int* __restrict__ ell, float* __restrict__ out) {
    __shared__ float red[4][2][GPN][132];            // 132-pad (16.5 KiB/block)
    const int wid  = threadIdx.x >> 6;
    const int lane = threadIdx.x & 63;
    const int h    = lane >> 5;                      // which node of the pair
    const int l32  = lane & 31;
    const int g    = (lane >> 3) & 3;                // group 0..3 within half
    const int hl   = lane & 7;                       // lane in group
    const int node = blockIdx.x * 8 + wid * 2 + h;   // grid exact: 5000*8 = 40000
    const int deg  = min(count[node], SLOTS);
    const int NIT  = (deg + GPN - 1) >> 2;
    int mx = max(NIT, __shfl_xor(NIT, 32));          // wave-uniform trip count
    const int* eb = ell + node * SLOTS;

    // prefetch all ELL indices, then their rinv (independent gathers, all in flight)
    int cidx[MAXIT];
    #pragma unroll
    for (int j = 0; j < MAXIT; j++) {
        int p = j * GPN + g;
        cidx[j] = (p < deg) ? eb[p] : node;
    }
    float rv[MAXIT];
    #pragma unroll
    for (int j = 0; j < MAXIT; j++) rv[j] = rinv[cidx[j]];

    const float* xrow = x + (size_t)node * D_FEAT;
    const float4* xn = (const float4*)xrow;
    float4 a0 = xn[hl], a1 = xn[8 + hl], a2 = xn[16 + hl], a3 = xn[24 + hl];
    const float b0    = beta[0];
    const float scale = b0 * rinv[node];             // beta / ||x_node||
    const float selfw = __expf(b0);                  // self-loop: cos = 1 -> alpha = beta
    float4 acc0 = {0,0,0,0}, acc1 = {0,0,0,0}, acc2 = {0,0,0,0}, acc3 = {0,0,0,0};
    float den = 0.f;

    // prologue: issue gathers for iterations 0,1,2 (one 128B line per group per instr)
    float4 A0, A1, A2, A3, B0, B1, B2, B3, C0, C1, C2, C3;
    {
        const float4* xc = (const float4*)(x + (size_t)cidx[0] * D_FEAT);
        A0 = xc[hl]; A1 = xc[8 + hl]; A2 = xc[16 + hl]; A3 = xc[24 + hl];
    }
    {
        const float4* xc = (const float4*)(x + (size_t)cidx[1] * D_FEAT);
        B0 = xc[hl]; B1 = xc[8 + hl]; B2 = xc[16 + hl]; B3 = xc[24 + hl];
    }
    {
        const float4* xc = (const float4*)(x + (size_t)cidx[2] * D_FEAT);
        C0 = xc[hl]; C1 = xc[8 + hl]; C2 = xc[16 + hl]; C3 = xc[24 + hl];
    }

    #pragma unroll
    for (int j = 0; j < MAXIT; j++) {
        if (j >= mx) break;                          // wave-uniform exit
        // dot via two running pairs (paired-fma friendly)
        float dx = 0.f, dy = 0.f;
        FMA2(a0.x, a0.y, A0.x, A0.y, 0, dx, dy);
        FMA2(a0.z, a0.w, A0.z, A0.w, 0, dx, dy);
        FMA2(a1.x, a1.y, A1.x, A1.y, 0, dx, dy);
        FMA2(a1.z, a1.w, A1.z, A1.w, 0, dx, dy);
        FMA2(a2.x, a2.y, A2.x, A2.y, 0, dx, dy);
        FMA2(a2.z, a2.w, A2.z, A2.w, 0, dx, dy);
        FMA2(a3.x, a3.y, A3.x, A3.y, 0, dx, dy);
        FMA2(a3.z, a3.w, A3.z, A3.w, 0, dx, dy);
        float dot = dx + dy;
        #pragma unroll
        for (int m = 1; m < 8; m <<= 1) dot += __shfl_xor(dot, m);   // 8-lane reduce
        float w = (j * GPN + g < deg) ? __expf(dot * scale * rv[j]) : 0.f;
        FMA2(A0.x, A0.y, w, w, 0, acc0.x, acc0.y);
        FMA2(A0.z, A0.w, w, w, 0, acc0.z, acc0.w);
        FMA2(A1.x, A1.y, w, w, 0, acc1.x, acc1.y);
        FMA2(A1.z, A1.w, w, w, 0, acc1.z, acc1.w);
        FMA2(A2.x, A2.y, w, w, 0, acc2.x, acc2.y);
        FMA2(A2.z, A2.w, w, w, 0, acc2.z, acc2.w);
        FMA2(A3.x, A3.y, w, w, 0, acc3.x, acc3.y);
        FMA2(A3.z, A3.w, w, w, 0, acc3.z, acc3.w);
        den += w;
        // rotate and issue gather for iteration j+3 (static index under full unroll)
        A0 = B0; A1 = B1; A2 = B2; A3 = B3;
        B0 = C0; B1 = C1; B2 = C2; B3 = C3;
        int cn = (j + 3 < MAXIT) ? cidx[j + 3] : node;
        const float4* xc = (const float4*)(x + (size_t)cn * D_FEAT);
        C0 = xc[hl]; C1 = xc[8 + hl]; C2 = xc[16 + hl]; C3 = xc[24 + hl];
    }

    // den: reduce across the 4 groups of this half (8,16 stay within the half)
    den += __shfl_xor(den, 8);
    den += __shfl_xor(den, 16);

    // epilogue: per-group partials to LDS (wave-private region, no barrier needed)
    {
        float4* rb = (float4*)red[wid][h][g];
        rb[     hl] = acc0;
        rb[ 8 + hl] = acc1;
        rb[16 + hl] = acc2;
        rb[24 + hl] = acc3;
    }
    float4 s = {0.f, 0.f, 0.f, 0.f};
    #pragma unroll
    for (int q = 0; q < GPN; q++) {
        float4 t = ((const float4*)red[wid][h][q])[l32];
        s.x += t.x; s.y += t.y; s.z += t.z; s.w += t.w;
    }
    float4 xs = ((const float4*)xrow)[l32];          // self features (cache-hot re-read)
    float inv = 1.0f / (den + selfw);
    float4 o = { (s.x + selfw * xs.x) * inv, (s.y + selfw * xs.y) * inv,
                 (s.z + selfw * xs.z) * inv, (s.w + selfw * xs.w) * inv };
    ((float4*)(out + (size_t)node * D_FEAT))[l32] = o;
}

extern "C" void kernel_launch(void* const* d_in, const int* in_sizes, int n_in,
                              void* d_out, int out_size, void* d_ws, size_t ws_size,
                              hipStream_t stream) {
    const float* x    = (const float*)d_in[0];
    const float* beta = (const float*)d_in[1];
    const int*   row  = (const int*)d_in[2];        // edge_index[0] = destination
    const int*   col  = row + N_EDGES;              // edge_index[1] = source
    float*       out  = (float*)d_out;

    // workspace layout (4B elements, ~8.2 MB total)
    int*   count = (int*)d_ws;                      // N
    float* rinv  = (float*)(count + N_NODES);       // N
    int*   ell   = (int*)(rinv + N_NODES);          // N * SLOTS

    zero_rinv_kernel<<<(N_NODES * 32) / 256, 256, 0, stream>>>(x, rinv, count);

    build_kernel<<<(N_EDGES + 255) / 256, 256, 0, stream>>>(row, col, count, ell);

    fused_kernel<<<N_NODES / 8, 256, 0, stream>>>(x, beta, rinv, count, ell, out);
}